// Round 6
// baseline (251.077 us; speedup 1.0000x reference)
//
#include <hip/hip_runtime.h>
#include <cstdint>
#include <cstring>

#define B_ 32
#define N_ 128
#define F_ 128
#define SPLIT_ 4

typedef __attribute__((ext_vector_type(8))) __bf16 bf16x8;
typedef __attribute__((ext_vector_type(4))) float f32x4;

__device__ inline uint16_t f2bf_bits(float f) {
  __bf16 h = (__bf16)f;
  uint16_t u;
  __builtin_memcpy(&u, &h, 2);
  return u;
}

// ---------------- Kernel A: e_v = v_in @ W_ev + b_ev  -> ws ----------------
__global__ __launch_bounds__(128) void ev_kernel(const float* __restrict__ v_in,
                                                 const float* __restrict__ W_ev,
                                                 const float* __restrict__ b_ev,
                                                 float* __restrict__ e_v) {
  __shared__ float vr[8][F_];
  const int R0 = blockIdx.x * 8;
  const int tid = threadIdx.x;  // output feature g
#pragma unroll
  for (int i = 0; i < 8; ++i) vr[i][tid] = v_in[(size_t)(R0 + i) * F_ + tid];
  __syncthreads();
  float acc[8];
  const float bb = b_ev[tid];
#pragma unroll
  for (int i = 0; i < 8; ++i) acc[i] = bb;
  for (int f = 0; f < F_; ++f) {
    const float wv = W_ev[f * F_ + tid];
#pragma unroll
    for (int i = 0; i < 8; ++i) acc[i] += vr[i][f] * wv;
  }
#pragma unroll
  for (int i = 0; i < 8; ++i) e_v[(size_t)(R0 + i) * F_ + tid] = acc[i];
}

// ------- Kernel P: pack W_e (fp32 [128][128]) into bf16 MFMA fragments ------
// Tile t = kt*8+gt. Lane l holds 8 bf16: W_e[kt*32 + 8*(l>>4) + e][gt*16 + (l&15)].
__global__ void pack_kernel(const float* __restrict__ W_e, uint32_t* __restrict__ wp) {
  const int idx = blockIdx.x * 256 + threadIdx.x;  // 0..2047
  const int t = idx >> 6, l = idx & 63;
  const int kt = t >> 3, gt = t & 7;
  const int kbase = kt * 32 + ((l >> 4) << 3);
  const int g = gt * 16 + (l & 15);
#pragma unroll
  for (int p = 0; p < 4; ++p) {
    const uint32_t lo = f2bf_bits(W_e[(kbase + 2 * p) * F_ + g]);
    const uint32_t hi = f2bf_bits(W_e[(kbase + 2 * p + 1) * F_ + g]);
    wp[idx * 4 + p] = lo | (hi << 16);
  }
}

// ---------------- Kernel M: fused edge GEMM + epilogue ----------------------
// grid = 32(b) * 8(n-tile) * 4(m-split), 256 threads = 4 fully INDEPENDENT
// waves (no LDS, no barriers).  Wave w owns g-tiles {2w,2w+1}; per iter it
// loads the 16n x 128k A-tile directly from global (per-lane dwordx4 pairs),
// rotated: loads(m+1) -> MFMA(m) -> epilogue/stores(m) -> cvt(m+1).
// evm loads are issued FIRST each iter (oldest in vmcnt FIFO) so waiting on
// them never drains the A-prefetch.
__global__ __launch_bounds__(256, 4) void main_kernel(
    const float* __restrict__ e_in, const float* __restrict__ e_v,
    const float* __restrict__ b_e, const bf16x8* __restrict__ wp,
    float* __restrict__ e_out, float* __restrict__ pve_part) {
  const int tid = threadIdx.x;
  const int w = tid >> 6, l = tid & 63;
  const int bid = blockIdx.x;
  const int s = bid & 3, nt = (bid >> 2) & 7, b = bid >> 5;
  const int n0 = nt * 16;
  const int lr = (l >> 4) << 2;  // g sub-base / D row group
  const int lc = l & 15;         // n within n-tile
  const int m0 = s * 32;

  // loop-invariant W fragments for this wave's 2 g-tiles (32 VGPRs)
  bf16x8 wreg[4][2];
#pragma unroll
  for (int kt = 0; kt < 4; ++kt)
#pragma unroll
    for (int j = 0; j < 2; ++j)
      wreg[kt][j] = wp[(kt * 8 + w * 2 + j) * 64 + l];

  // loop-invariant row term: e_v[b][n0+lc][g] + b_e[g]
  f32x4 evn[2];
#pragma unroll
  for (int j = 0; j < 2; ++j) {
    const int g0 = (w * 2 + j) * 16 + lr;
    evn[j] = *reinterpret_cast<const f32x4*>(&e_v[(size_t)(b * N_ + n0 + lc) * F_ + g0]) +
             *reinterpret_cast<const f32x4*>(&b_e[g0]);
  }

  f32x4 pve[2];
#pragma unroll
  for (int j = 0; j < 2; ++j) { pve[j][0] = 0.f; pve[j][1] = 0.f; pve[j][2] = 0.f; pve[j][3] = 0.f; }

  // per-lane bases: n = n0+lc row, k base = (l>>4)*8
  const float* lane_in =
      e_in + (((size_t)b * N_ + m0) * N_ + (n0 + lc)) * F_ + ((l >> 4) << 3);
  float* lane_out = e_out + (((size_t)b * N_ + m0) * N_ + (n0 + lc)) * F_;
  const float* evb = e_v + (size_t)b * N_ * F_;

  f32x4 f[8];   // fp32 A staging (32 VGPRs)
  bf16x8 a[4];  // bf16 A fragments (16 VGPRs)

#define LOADS(itn)                                                        \
  {                                                                       \
    const float* p_ = lane_in + (size_t)(itn) * (N_ * F_);                \
    _Pragma("unroll") for (int kt_ = 0; kt_ < 4; ++kt_) {                 \
      f[kt_ * 2] = *reinterpret_cast<const f32x4*>(p_ + kt_ * 32);        \
      f[kt_ * 2 + 1] = *reinterpret_cast<const f32x4*>(p_ + kt_ * 32 + 4);\
    }                                                                     \
  }
#define CVT()                                                             \
  {                                                                       \
    _Pragma("unroll") for (int kt_ = 0; kt_ < 4; ++kt_) {                 \
      _Pragma("unroll") for (int e_ = 0; e_ < 4; ++e_) {                  \
        a[kt_][e_] = (__bf16)f[kt_ * 2][e_];                              \
        a[kt_][e_ + 4] = (__bf16)f[kt_ * 2 + 1][e_];                      \
      }                                                                   \
    }                                                                     \
  }

  LOADS(0);
  CVT();

  for (int it = 0; it < 32; ++it) {
    const int m = m0 + it;

    // evm loads first (oldest in FIFO -> waiting them leaves prefetch in flight)
    f32x4 acc[2];
#pragma unroll
    for (int j = 0; j < 2; ++j) {
      const int g0 = (w * 2 + j) * 16 + lr;
      const f32x4 evm = *reinterpret_cast<const f32x4*>(&evb[(size_t)m * F_ + g0]);
      acc[j] = evn[j] + evm;  // seed MFMA C-input with the bias terms
    }

    if (it < 31) LOADS(it + 1);  // A-prefetch for next iter (8 dwordx4)

#pragma unroll
    for (int kt = 0; kt < 4; ++kt) {
      acc[0] = __builtin_amdgcn_mfma_f32_16x16x32_bf16(wreg[kt][0], a[kt], acc[0], 0, 0, 0);
      acc[1] = __builtin_amdgcn_mfma_f32_16x16x32_bf16(wreg[kt][1], a[kt], acc[1], 0, 0, 0);
    }

    float* op = lane_out + (size_t)it * (N_ * F_);
#pragma unroll
    for (int j = 0; j < 2; ++j) {
      const int g0 = (w * 2 + j) * 16 + lr;
      f32x4 v = acc[j];
#pragma unroll
      for (int q = 0; q < 4; ++q) v[q] = fmaxf(v[q], 0.f);
      pve[j] += v;
      *reinterpret_cast<f32x4*>(&op[g0]) = v;
    }

    if (it < 31) CVT();  // convert next tile (waits its loads, under store shadow)
  }
#undef LOADS
#undef CVT

  // wave owns its g-slice: write partial per_v_e directly
  float* pp = pve_part + (((size_t)s * B_ + b) * N_ + n0 + lc) * F_;
#pragma unroll
  for (int j = 0; j < 2; ++j)
    *reinterpret_cast<f32x4*>(&pp[(w * 2 + j) * 16 + lr]) = pve[j];
}

// ---------------- Kernel V: v_out = relu([sum(pve), v_in] @ W_v + b_v) ------
__global__ __launch_bounds__(128) void v_kernel(
    const float* __restrict__ v_in, const float* __restrict__ pve_part,
    const float* __restrict__ W_v, const float* __restrict__ b_v,
    float* __restrict__ v_out) {
  __shared__ float rows[8][256];
  const int R0 = blockIdx.x * 8;
  const int tid = threadIdx.x;
#pragma unroll
  for (int i = 0; i < 8; ++i) {
    const size_t r = R0 + i;
    float acc = 0.f;
#pragma unroll
    for (int s = 0; s < SPLIT_; ++s)
      acc += pve_part[((size_t)s * B_ * N_ + r) * F_ + tid];
    rows[i][tid] = acc;
    rows[i][128 + tid] = v_in[r * F_ + tid];
  }
  __syncthreads();
  float acc[8];
  const float bb = b_v[tid];
#pragma unroll
  for (int i = 0; i < 8; ++i) acc[i] = bb;
  for (int f = 0; f < 256; ++f) {
    const float wv = W_v[f * F_ + tid];
#pragma unroll
    for (int i = 0; i < 8; ++i) acc[i] += rows[i][f] * wv;
  }
#pragma unroll
  for (int i = 0; i < 8; ++i)
    v_out[(size_t)(R0 + i) * F_ + tid] = fmaxf(acc[i], 0.f);
}

extern "C" void kernel_launch(void* const* d_in, const int* in_sizes, int n_in,
                              void* d_out, int out_size, void* d_ws, size_t ws_size,
                              hipStream_t stream) {
  const float* v_in = (const float*)d_in[0];
  const float* e_in = (const float*)d_in[1];
  const float* W_ev = (const float*)d_in[2];
  const float* b_ev = (const float*)d_in[3];
  const float* W_e  = (const float*)d_in[4];
  const float* b_e  = (const float*)d_in[5];
  const float* W_v  = (const float*)d_in[6];
  const float* b_v  = (const float*)d_in[7];

  float* out = (float*)d_out;
  float* v_out = out;                         // [32,128,128]
  float* e_out = out + (size_t)B_ * N_ * F_;  // [32,128,128,128]

  char* ws = (char*)d_ws;
  float* e_v = (float*)ws;                                   // 2 MB
  uint32_t* wpack = (uint32_t*)(ws + (size_t)2097152);       // 32 KB
  float* pve_part = (float*)(ws + (size_t)2097152 + 65536);  // 8 MB

  ev_kernel<<<(B_ * N_) / 8, 128, 0, stream>>>(v_in, W_ev, b_ev, e_v);
  pack_kernel<<<8, 256, 0, stream>>>(W_e, wpack);
  main_kernel<<<B_ * 8 * SPLIT_, 256, 0, stream>>>(e_in, e_v, b_e,
                                                   (const bf16x8*)wpack,
                                                   e_out, pve_part);
  v_kernel<<<(B_ * N_) / 8, 128, 0, stream>>>(v_in, pve_part, W_v, b_v, v_out);
}

// Round 7
// 231.770 us; speedup vs baseline: 1.0833x; 1.0833x over previous
//
#include <hip/hip_runtime.h>
#include <cstdint>
#include <cstring>

#define B_ 32
#define N_ 128
#define F_ 128
#define SPLIT_ 8

typedef __attribute__((ext_vector_type(8))) __bf16 bf16x8;
typedef __attribute__((ext_vector_type(4))) float f32x4;

__device__ inline uint16_t f2bf_bits(float f) {
  __bf16 h = (__bf16)f;
  uint16_t u;
  __builtin_memcpy(&u, &h, 2);
  return u;
}

// ---------------- Kernel A: e_v = v_in @ W_ev + b_ev  -> ws ----------------
__global__ __launch_bounds__(128) void ev_kernel(const float* __restrict__ v_in,
                                                 const float* __restrict__ W_ev,
                                                 const float* __restrict__ b_ev,
                                                 float* __restrict__ e_v) {
  __shared__ float vr[8][F_];
  const int R0 = blockIdx.x * 8;
  const int tid = threadIdx.x;  // output feature g
#pragma unroll
  for (int i = 0; i < 8; ++i) vr[i][tid] = v_in[(size_t)(R0 + i) * F_ + tid];
  __syncthreads();
  float acc[8];
  const float bb = b_ev[tid];
#pragma unroll
  for (int i = 0; i < 8; ++i) acc[i] = bb;
  for (int f = 0; f < F_; ++f) {
    const float wv = W_ev[f * F_ + tid];
#pragma unroll
    for (int i = 0; i < 8; ++i) acc[i] += vr[i][f] * wv;
  }
#pragma unroll
  for (int i = 0; i < 8; ++i) e_v[(size_t)(R0 + i) * F_ + tid] = acc[i];
}

// ------- Kernel P: pack W_e (fp32 [128][128]) into bf16 MFMA fragments ------
// Tile t = kt*8+gt. Lane l holds 8 bf16: W_e[kt*32 + 8*(l>>4) + e][gt*16 + (l&15)].
__global__ void pack_kernel(const float* __restrict__ W_e, uint32_t* __restrict__ wp) {
  const int idx = blockIdx.x * 256 + threadIdx.x;  // 0..2047
  const int t = idx >> 6, l = idx & 63;
  const int kt = t >> 3, gt = t & 7;
  const int kbase = kt * 32 + ((l >> 4) << 3);
  const int g = gt * 16 + (l & 15);
#pragma unroll
  for (int p = 0; p < 4; ++p) {
    const uint32_t lo = f2bf_bits(W_e[(kbase + 2 * p) * F_ + g]);
    const uint32_t hi = f2bf_bits(W_e[(kbase + 2 * p + 1) * F_ + g]);
    wp[idx * 4 + p] = lo | (hi << 16);
  }
}

// ---------------- Kernel M: fused edge GEMM + epilogue ----------------------
// grid = 2048: phys block -> nt = bid>>8 (low-order dispatch: adjacent blocks
// on one XCD share (b,s) and cover adjacent nt => adjacent 8KB reads).
// 256 threads = 4 independent waves (no LDS/barriers). Wave w owns g-tiles
// {2w,2w+1}; 16-iter m-loop; enforced rotation (sched_barrier-pinned):
//   [LOADS(it+1) x8][evm(it+1) x2] MFMA(it) epilogue stores(it) CVT(it+1)
// All waits are counted; stores are never drained inside the loop.
__global__ __launch_bounds__(256, 4) void main_kernel(
    const float* __restrict__ e_in, const float* __restrict__ e_v,
    const float* __restrict__ b_e, const bf16x8* __restrict__ wp,
    float* __restrict__ e_out, float* __restrict__ pve_part) {
  const int tid = threadIdx.x;
  const int w = tid >> 6, l = tid & 63;
  const int phys = blockIdx.x;
  const int nt = phys >> 8;        // 0..7
  const int grp = phys & 255;
  const int b = grp >> 3;          // 0..31
  const int s = grp & 7;           // 0..7  (XCD = s under %8 round-robin)
  const int n0 = nt * 16;
  const int lr = (l >> 4) << 2;    // g sub-base / D row group
  const int lc = l & 15;           // n within n-tile
  const int m0 = s * 16;

  // loop-invariant W fragments for this wave's 2 g-tiles (32 VGPRs)
  bf16x8 wreg[4][2];
#pragma unroll
  for (int kt = 0; kt < 4; ++kt)
#pragma unroll
    for (int j = 0; j < 2; ++j)
      wreg[kt][j] = wp[(kt * 8 + w * 2 + j) * 64 + l];

  // loop-invariant row term: e_v[b][n0+lc][g] + b_e[g]
  f32x4 evn[2];
#pragma unroll
  for (int j = 0; j < 2; ++j) {
    const int g0 = (w * 2 + j) * 16 + lr;
    evn[j] = *reinterpret_cast<const f32x4*>(&e_v[(size_t)(b * N_ + n0 + lc) * F_ + g0]) +
             *reinterpret_cast<const f32x4*>(&b_e[g0]);
  }

  f32x4 pve[2];
#pragma unroll
  for (int j = 0; j < 2; ++j) { pve[j][0] = 0.f; pve[j][1] = 0.f; pve[j][2] = 0.f; pve[j][3] = 0.f; }

  const float* lane_in =
      e_in + (((size_t)b * N_ + m0) * N_ + (n0 + lc)) * F_ + ((l >> 4) << 3);
  float* lane_out = e_out + (((size_t)b * N_ + m0) * N_ + (n0 + lc)) * F_;
  const float* evb = e_v + (size_t)b * N_ * F_;

  f32x4 f[8];        // fp32 A staging (32 VGPRs)
  bf16x8 a[4];       // bf16 A fragments (16 VGPRs)
  f32x4 evmC[2], evmN[2];

#define LOADS(itn)                                                         \
  {                                                                        \
    const float* p_ = lane_in + (size_t)(itn) * (N_ * F_);                 \
    _Pragma("unroll") for (int kt_ = 0; kt_ < 4; ++kt_) {                  \
      f[kt_ * 2] = *reinterpret_cast<const f32x4*>(p_ + kt_ * 32);         \
      f[kt_ * 2 + 1] = *reinterpret_cast<const f32x4*>(p_ + kt_ * 32 + 4); \
    }                                                                      \
  }
#define EVML(dst, mm)                                                      \
  {                                                                        \
    _Pragma("unroll") for (int j_ = 0; j_ < 2; ++j_) {                     \
      const int g0_ = (w * 2 + j_) * 16 + lr;                              \
      dst[j_] = *reinterpret_cast<const f32x4*>(&evb[(size_t)(mm) * F_ + g0_]); \
    }                                                                      \
  }
#define CVT()                                                              \
  {                                                                        \
    _Pragma("unroll") for (int kt_ = 0; kt_ < 4; ++kt_) {                  \
      _Pragma("unroll") for (int e_ = 0; e_ < 4; ++e_) {                   \
        a[kt_][e_] = (__bf16)f[kt_ * 2][e_];                               \
        a[kt_][e_ + 4] = (__bf16)f[kt_ * 2 + 1][e_];                       \
      }                                                                    \
    }                                                                      \
  }

  // prologue
  LOADS(0);
  EVML(evmC, m0);
  CVT();

  for (int it = 0; it < 16; ++it) {
    // prefetch next A-tile + next evm; pin issue point
    if (it < 15) {
      LOADS(it + 1);
      EVML(evmN, m0 + it + 1);
    }
    __builtin_amdgcn_sched_barrier(0);

    f32x4 acc[2];
#pragma unroll
    for (int j = 0; j < 2; ++j) acc[j] = evn[j] + evmC[j];  // seed with bias terms
#pragma unroll
    for (int kt = 0; kt < 4; ++kt) {
      acc[0] = __builtin_amdgcn_mfma_f32_16x16x32_bf16(wreg[kt][0], a[kt], acc[0], 0, 0, 0);
      acc[1] = __builtin_amdgcn_mfma_f32_16x16x32_bf16(wreg[kt][1], a[kt], acc[1], 0, 0, 0);
    }

    float* op = lane_out + (size_t)it * (N_ * F_);
#pragma unroll
    for (int j = 0; j < 2; ++j) {
      const int g0 = (w * 2 + j) * 16 + lr;
      f32x4 v = acc[j];
#pragma unroll
      for (int q = 0; q < 4; ++q) v[q] = fmaxf(v[q], 0.f);
      pve[j] += v;
      *reinterpret_cast<f32x4*>(&op[g0]) = v;
    }
    __builtin_amdgcn_sched_barrier(0);

    if (it < 15) {
      CVT();  // waits L(it+1) only (counted; stores/evm stay in flight)
#pragma unroll
      for (int j = 0; j < 2; ++j) evmC[j] = evmN[j];
    }
    __builtin_amdgcn_sched_barrier(0);
  }
#undef LOADS
#undef EVML
#undef CVT

  // wave owns its g-slice: write partial per_v_e directly
  float* pp = pve_part + (((size_t)s * B_ + b) * N_ + n0 + lc) * F_;
#pragma unroll
  for (int j = 0; j < 2; ++j)
    *reinterpret_cast<f32x4*>(&pp[(w * 2 + j) * 16 + lr]) = pve[j];
}

// ---------------- Kernel V: v_out = relu([sum(pve), v_in] @ W_v + b_v) ------
__global__ __launch_bounds__(128) void v_kernel(
    const float* __restrict__ v_in, const float* __restrict__ pve_part,
    const float* __restrict__ W_v, const float* __restrict__ b_v,
    float* __restrict__ v_out) {
  __shared__ float rows[8][256];
  const int R0 = blockIdx.x * 8;
  const int tid = threadIdx.x;
#pragma unroll
  for (int i = 0; i < 8; ++i) {
    const size_t r = R0 + i;
    float acc = 0.f;
#pragma unroll
    for (int s = 0; s < SPLIT_; ++s)
      acc += pve_part[((size_t)s * B_ * N_ + r) * F_ + tid];
    rows[i][tid] = acc;
    rows[i][128 + tid] = v_in[r * F_ + tid];
  }
  __syncthreads();
  float acc[8];
  const float bb = b_v[tid];
#pragma unroll
  for (int i = 0; i < 8; ++i) acc[i] = bb;
  for (int f = 0; f < 256; ++f) {
    const float wv = W_v[f * F_ + tid];
#pragma unroll
    for (int i = 0; i < 8; ++i) acc[i] += rows[i][f] * wv;
  }
#pragma unroll
  for (int i = 0; i < 8; ++i)
    v_out[(size_t)(R0 + i) * F_ + tid] = fmaxf(acc[i], 0.f);
}

extern "C" void kernel_launch(void* const* d_in, const int* in_sizes, int n_in,
                              void* d_out, int out_size, void* d_ws, size_t ws_size,
                              hipStream_t stream) {
  const float* v_in = (const float*)d_in[0];
  const float* e_in = (const float*)d_in[1];
  const float* W_ev = (const float*)d_in[2];
  const float* b_ev = (const float*)d_in[3];
  const float* W_e  = (const float*)d_in[4];
  const float* b_e  = (const float*)d_in[5];
  const float* W_v  = (const float*)d_in[6];
  const float* b_v  = (const float*)d_in[7];

  float* out = (float*)d_out;
  float* v_out = out;                         // [32,128,128]
  float* e_out = out + (size_t)B_ * N_ * F_;  // [32,128,128,128]

  char* ws = (char*)d_ws;
  float* e_v = (float*)ws;                                   // 2 MB
  uint32_t* wpack = (uint32_t*)(ws + (size_t)2097152);       // 64 KB slot
  float* pve_part = (float*)(ws + (size_t)2097152 + 65536);  // 16 MB

  ev_kernel<<<(B_ * N_) / 8, 128, 0, stream>>>(v_in, W_ev, b_ev, e_v);
  pack_kernel<<<8, 256, 0, stream>>>(W_e, wpack);
  main_kernel<<<B_ * 8 * SPLIT_, 256, 0, stream>>>(e_in, e_v, b_e,
                                                   (const bf16x8*)wpack,
                                                   e_out, pve_part);
  v_kernel<<<(B_ * N_) / 8, 128, 0, stream>>>(v_in, pve_part, W_v, b_v, v_out);
}